// Round 2
// baseline (5075.290 us; speedup 1.0000x reference)
//
#include <hip/hip_runtime.h>

#define SEQ 512
#define NB  16
#define DIM 768
#define NH  12
#define HDIM 64
#define NL  12
#define FFD 3072
#define MTOK 8192   // NB*SEQ

typedef _Float16 half8 __attribute__((ext_vector_type(8)));
typedef float    floatx4 __attribute__((ext_vector_type(4)));

__device__ __forceinline__ void load_lds16(const void* g, void* l) {
  __builtin_amdgcn_global_load_lds((__attribute__((address_space(1))) void*)g,
                                   (__attribute__((address_space(3))) void*)l, 16, 0, 0);
}

// ---------------------------------------------------------------- block LN
__device__ __forceinline__ float blockSum768(float v) {
  __shared__ float red[4];
  #pragma unroll
  for (int d = 32; d; d >>= 1) v += __shfl_xor(v, d);
  const int wv = threadIdx.x >> 6;
  __syncthreads();                 // protect red from previous use
  if ((threadIdx.x & 63) == 0) red[wv] = v;
  __syncthreads();
  return red[0] + red[1] + red[2] + red[3];
}

__device__ __forceinline__ void ln_store(float x0, float x1, float x2,
                                         const float* __restrict__ g,
                                         const float* __restrict__ bb,
                                         float* __restrict__ yf,
                                         _Float16* __restrict__ yh, int row) {
  const int tid = threadIdx.x;
  const float mu = blockSum768(x0 + x1 + x2) * (1.0f / 768.0f);
  const float d0 = x0 - mu, d1 = x1 - mu, d2 = x2 - mu;
  const float var = blockSum768(d0 * d0 + d1 * d1 + d2 * d2) * (1.0f / 768.0f);
  const float inv = rsqrtf(var + 1e-12f);
  const size_t base = (size_t)row * DIM;
  const float y0 = d0 * inv * g[tid]       + bb[tid];
  const float y1 = d1 * inv * g[tid + 256] + bb[tid + 256];
  const float y2 = d2 * inv * g[tid + 512] + bb[tid + 512];
  if (yf) { yf[base + tid] = y0; yf[base + tid + 256] = y1; yf[base + tid + 512] = y2; }
  yh[base + tid] = (_Float16)y0; yh[base + tid + 256] = (_Float16)y1; yh[base + tid + 512] = (_Float16)y2;
}

// ---------------------------------------------------------------- kernels
__global__ __launch_bounds__(256) void embed_ln_k(const int* __restrict__ ids,
                                                  const float* __restrict__ we,
                                                  const float* __restrict__ pe,
                                                  const float* __restrict__ g,
                                                  const float* __restrict__ bb,
                                                  float* __restrict__ hf,
                                                  _Float16* __restrict__ hh) {
  const int tok = blockIdx.x;
  const int s = tok & (SEQ - 1);
  const int id = ids[tok];
  const int tid = threadIdx.x;
  float x[3];
  #pragma unroll
  for (int j = 0; j < 3; ++j) {
    const int d = tid + j * 256;
    x[j] = we[(size_t)id * DIM + d] + pe[(size_t)s * DIM + d];
  }
  ln_store(x[0], x[1], x[2], g, bb, hf, hh, tok);
}

__global__ __launch_bounds__(256) void ln_k(const float* __restrict__ xin,
                                            const float* __restrict__ g,
                                            const float* __restrict__ bb,
                                            float* __restrict__ yf,
                                            _Float16* __restrict__ yh) {
  const int row = blockIdx.x;
  const int tid = threadIdx.x;
  float x[3];
  #pragma unroll
  for (int j = 0; j < 3; ++j) x[j] = xin[(size_t)row * DIM + tid + j * 256];
  ln_store(x[0], x[1], x[2], g, bb, yf, yh, row);
}

// transpose+convert: in f32 [z][K][N] -> out f16 [z][N][K]
__global__ __launch_bounds__(256) void transpose_k(const float* __restrict__ in,
                                                   _Float16* __restrict__ out,
                                                   int K, int N) {
  __shared__ float tile[32][33];
  const int z = blockIdx.z;
  in  += (size_t)z * K * N;
  out += (size_t)z * K * N;
  const int n0 = blockIdx.x * 32, k0 = blockIdx.y * 32;
  const int tx = threadIdx.x & 31, ty = threadIdx.x >> 5;   // ty 0..7
  #pragma unroll
  for (int i = 0; i < 32; i += 8) tile[ty + i][tx] = in[(size_t)(k0 + ty + i) * N + n0 + tx];
  __syncthreads();
  #pragma unroll
  for (int i = 0; i < 32; i += 8) out[(size_t)(n0 + ty + i) * K + k0 + tx] = (_Float16)tile[tx][ty + i];
}

// position-coefficient modulation ps[l][b][s]
__global__ __launch_bounds__(512) void ps_k(const int* __restrict__ epid,
                                            const float* __restrict__ coef,
                                            float* __restrict__ ps_all) {
  __shared__ int red[8];
  const int b = blockIdx.x, tid = threadIdx.x;
  int e = (tid < 256) ? epid[b * 256 + tid] : 0;
  #pragma unroll
  for (int d = 32; d; d >>= 1) e = max(e, __shfl_xor(e, d));
  if ((tid & 63) == 0) red[tid >> 6] = e;
  __syncthreads();
  int turn = red[0];
  #pragma unroll
  for (int i = 1; i < 8; ++i) turn = max(turn, red[i]);
  int row = (turn - 1) >> 1;
  row = max(0, min(4, row));
  const int pe = (tid < 256) ? epid[b * 256 + tid] : 11;
  #pragma unroll
  for (int l = 0; l < NL; ++l)
    ps_all[((size_t)l * NB + b) * SEQ + tid] = coef[(l * 5 + row) * 12 + pe];
}

// ------------------------------------------------------- generic f16 GEMM
// C[M,N] = A[M,K] @ Bt[N,K]^T (+bias, +resid, gelu) ; 128x128 tile, 4 waves
template <bool RES, bool GELU, bool WF, bool WH>
__global__ __launch_bounds__(256) void gemm_f16(const _Float16* __restrict__ A,
                                                const _Float16* __restrict__ Bt,
                                                const float* __restrict__ bias,
                                                const float* __restrict__ resid,
                                                float* __restrict__ outF,
                                                _Float16* __restrict__ outH,
                                                int M, int N, int K) {
  __shared__ __align__(16) _Float16 Als[128 * 32];
  __shared__ __align__(16) _Float16 Bls[128 * 32];
  const int tid = threadIdx.x, lane = tid & 63, wave = tid >> 6;
  const int bm0 = blockIdx.y * 128, bn0 = blockIdx.x * 128;
  const int lr = lane & 15, lk = lane >> 4;
  const int wm = (wave >> 1) * 64, wn = (wave & 1) * 64;
  floatx4 acc[4][4] = {};

  const int srow = lane >> 2;            // 0..15
  const int scol = (lane & 3) * 8;       // 0/8/16/24
  const _Float16* Ag = A  + (size_t)(bm0 + wave * 16 + srow) * K + scol;
  const _Float16* Bg = Bt + (size_t)(bn0 + wave * 16 + srow) * K + scol;
  _Float16* Al = &Als[wave * 16 * 32];
  _Float16* Bl = &Bls[wave * 16 * 32];
  const size_t rs64 = (size_t)64 * K;

  for (int kt = 0; kt < K; kt += 32) {
    load_lds16(Ag + kt,        Al);
    load_lds16(Ag + rs64 + kt, Al + 64 * 32);
    load_lds16(Bg + kt,        Bl);
    load_lds16(Bg + rs64 + kt, Bl + 64 * 32);
    __syncthreads();
    half8 af[4], bf[4];
    #pragma unroll
    for (int i = 0; i < 4; ++i) {
      af[i] = *(const half8*)&Als[(wm + i * 16 + lr) * 32 + lk * 8];
      bf[i] = *(const half8*)&Bls[(wn + i * 16 + lr) * 32 + lk * 8];
    }
    #pragma unroll
    for (int mi = 0; mi < 4; ++mi)
      #pragma unroll
      for (int ni = 0; ni < 4; ++ni)
        acc[mi][ni] = __builtin_amdgcn_mfma_f32_16x16x32_f16(af[mi], bf[ni], acc[mi][ni], 0, 0, 0);
    __syncthreads();
  }

  #pragma unroll
  for (int mi = 0; mi < 4; ++mi) {
    #pragma unroll
    for (int r = 0; r < 4; ++r) {
      const int row = bm0 + wm + mi * 16 + lk * 4 + r;
      const size_t ro = (size_t)row * N;
      #pragma unroll
      for (int ni = 0; ni < 4; ++ni) {
        const int col = bn0 + wn + ni * 16 + lr;
        float x = acc[mi][ni][r] + bias[col];
        if (RES)  x += resid[ro + col];
        if (GELU) x = 0.5f * x * (1.0f + erff(x * 0.70710678118654752f));
        if (WF) outF[ro + col] = x;
        if (WH) outH[ro + col] = (_Float16)x;
      }
    }
  }
}

// ------------------------------------------------------- flash attention
// grid (qt=4, h=12, b=16), 256 threads; wave w owns q-rows qt*128+w*32..+32
__global__ __launch_bounds__(256) void attn_k(const _Float16* __restrict__ q,
                                              const _Float16* __restrict__ k,
                                              const _Float16* __restrict__ v,
                                              const float* __restrict__ ps,
                                              const float* __restrict__ mask,
                                              _Float16* __restrict__ ctx) {
  __shared__ __align__(16) _Float16 kls[64 * 64];
  __shared__ __align__(16) _Float16 vtls[64 * 64];
  __shared__ __align__(16) _Float16 pls[4][32 * 64];
  const int tid = threadIdx.x, lane = tid & 63, wave = tid >> 6;
  const int qt = blockIdx.x, h = blockIdx.y, b = blockIdx.z;
  const int lr = lane & 15, lk = lane >> 4;
  const int q0 = qt * 128 + wave * 32;

  half8 qf[2][2];
  #pragma unroll
  for (int mi = 0; mi < 2; ++mi)
    #pragma unroll
    for (int ks = 0; ks < 2; ++ks)
      qf[mi][ks] = *(const half8*)&q[(size_t)(b * SEQ + q0 + mi * 16 + lr) * DIM + h * HDIM + ks * 32 + lk * 8];

  floatx4 o[2][4] = {};
  float m_run[2][4], l_run[2][4], mq[2][4];
  #pragma unroll
  for (int mi = 0; mi < 2; ++mi)
    #pragma unroll
    for (int r = 0; r < 4; ++r) {
      m_run[mi][r] = -3e38f; l_run[mi][r] = 0.f;
      mq[mi][r] = mask[b * SEQ + q0 + mi * 16 + lk * 4 + r];
    }

  const int nt = 2 * (qt + 1);
  for (int t = 0; t < nt; ++t) {
    const int kb = t * 64;
    // stage K tile and V^T tile
    #pragma unroll
    for (int i = 0; i < 2; ++i) {
      const int idx = tid + i * 256;
      const int key = idx >> 3, c8 = (idx & 7) * 8;
      const size_t gkv = (size_t)(b * SEQ + kb + key) * DIM + h * HDIM + c8;
      *(half8*)&kls[key * 64 + c8] = *(const half8*)&k[gkv];
      half8 vv = *(const half8*)&v[gkv];
      #pragma unroll
      for (int j = 0; j < 8; ++j) vtls[(c8 + j) * 64 + key] = vv[j];
    }
    __syncthreads();

    // S = Q K^T
    floatx4 s[2][4] = {};
    #pragma unroll
    for (int ks = 0; ks < 2; ++ks)
      #pragma unroll
      for (int ni = 0; ni < 4; ++ni) {
        half8 kf = *(const half8*)&kls[(ni * 16 + lr) * 64 + ks * 32 + lk * 8];
        #pragma unroll
        for (int mi = 0; mi < 2; ++mi)
          s[mi][ni] = __builtin_amdgcn_mfma_f32_16x16x32_f16(qf[mi][ks], kf, s[mi][ni], 0, 0, 0);
      }

    float pk[4], km[4]; int kidx[4];
    #pragma unroll
    for (int ni = 0; ni < 4; ++ni) {
      kidx[ni] = kb + ni * 16 + lr;
      pk[ni] = ps[b * SEQ + kidx[ni]] * 0.125f;
      km[ni] = mask[b * SEQ + kidx[ni]];
    }

    #pragma unroll
    for (int mi = 0; mi < 2; ++mi) {
      #pragma unroll
      for (int r = 0; r < 4; ++r) {
        const int rq = q0 + mi * 16 + lk * 4 + r;
        float sc[4]; float mt = -3e38f;
        #pragma unroll
        for (int ni = 0; ni < 4; ++ni) {
          const float am = (kidx[ni] <= rq) ? km[ni] * mq[mi][r] : 0.f;
          const float x = s[mi][ni][r] * pk[ni] * am - 1e10f * (1.f - am);
          sc[ni] = x; mt = fmaxf(mt, x);
        }
        #pragma unroll
        for (int d = 1; d < 16; d <<= 1) mt = fmaxf(mt, __shfl_xor(mt, d));
        const float mnew = fmaxf(m_run[mi][r], mt);
        const float corr = __expf(m_run[mi][r] - mnew);
        float rsum = 0.f;
        #pragma unroll
        for (int ni = 0; ni < 4; ++ni) {
          const float p = __expf(sc[ni] - mnew);
          rsum += p;
          pls[wave][(mi * 16 + lk * 4 + r) * 64 + ni * 16 + lr] = (_Float16)p;
        }
        #pragma unroll
        for (int d = 1; d < 16; d <<= 1) rsum += __shfl_xor(rsum, d);
        l_run[mi][r] = l_run[mi][r] * corr + rsum;
        m_run[mi][r] = mnew;
        #pragma unroll
        for (int ni = 0; ni < 4; ++ni) o[mi][ni][r] *= corr;
      }
    }

    // O += P V
    #pragma unroll
    for (int mi = 0; mi < 2; ++mi) {
      half8 pf[2];
      #pragma unroll
      for (int ks = 0; ks < 2; ++ks)
        pf[ks] = *(const half8*)&pls[wave][(mi * 16 + lr) * 64 + ks * 32 + lk * 8];
      #pragma unroll
      for (int ni = 0; ni < 4; ++ni)
        #pragma unroll
        for (int ks = 0; ks < 2; ++ks)
          o[mi][ni] = __builtin_amdgcn_mfma_f32_16x16x32_f16(
              pf[ks], *(const half8*)&vtls[(ni * 16 + lr) * 64 + ks * 32 + lk * 8], o[mi][ni], 0, 0, 0);
    }
    __syncthreads();
  }

  #pragma unroll
  for (int mi = 0; mi < 2; ++mi)
    #pragma unroll
    for (int r = 0; r < 4; ++r) {
      const float inv = 1.f / l_run[mi][r];
      const int rq = q0 + mi * 16 + lk * 4 + r;
      #pragma unroll
      for (int ni = 0; ni < 4; ++ni)
        ctx[(size_t)(b * SEQ + rq) * DIM + h * HDIM + ni * 16 + lr] = (_Float16)(o[mi][ni][r] * inv);
    }
}

// ---------------------------------------------------------------- launch
extern "C" void kernel_launch(void* const* d_in, const int* in_sizes, int n_in,
                              void* d_out, int out_size, void* d_ws, size_t ws_size,
                              hipStream_t stream) {
  const int*   ids  = (const int*)d_in[0];
  const float* mask = (const float*)d_in[1];
  const int*   epid = (const int*)d_in[2];
  const float* we   = (const float*)d_in[3];
  const float* pe   = (const float*)d_in[4];
  const float* elng = (const float*)d_in[5];
  const float* elnb = (const float*)d_in[6];
  const float* Wq   = (const float*)d_in[7];  const float* bq  = (const float*)d_in[8];
  const float* Wk   = (const float*)d_in[9];  const float* bk  = (const float*)d_in[10];
  const float* Wv   = (const float*)d_in[11]; const float* bv  = (const float*)d_in[12];
  const float* Wo   = (const float*)d_in[13]; const float* bo  = (const float*)d_in[14];
  const float* ln1g = (const float*)d_in[15]; const float* ln1b = (const float*)d_in[16];
  const float* Wi   = (const float*)d_in[17]; const float* bi  = (const float*)d_in[18];
  const float* Wo2  = (const float*)d_in[19]; const float* bo2 = (const float*)d_in[20];
  const float* ln2g = (const float*)d_in[21]; const float* ln2b = (const float*)d_in[22];
  const float* coef = (const float*)d_in[23];
  float* out = (float*)d_out;

  char* w = (char*)d_ws;
  auto alloc = [&](size_t bytes) { char* p = w; w += (bytes + 255) & ~(size_t)255; return p; };
  const size_t WSM = (size_t)DIM * DIM;     // 589824
  const size_t WLG = (size_t)DIM * FFD;     // 2359296
  _Float16* wqT  = (_Float16*)alloc(NL * WSM * 2);
  _Float16* wkT  = (_Float16*)alloc(NL * WSM * 2);
  _Float16* wvT  = (_Float16*)alloc(NL * WSM * 2);
  _Float16* woT  = (_Float16*)alloc(NL * WSM * 2);
  _Float16* wiT  = (_Float16*)alloc(NL * WLG * 2);
  _Float16* wo2T = (_Float16*)alloc(NL * WLG * 2);
  float*    h_f32 = (float*)alloc((size_t)MTOK * DIM * 4);
  _Float16* h_f16 = (_Float16*)alloc((size_t)MTOK * DIM * 2);
  float*    a_f32 = (float*)alloc((size_t)MTOK * DIM * 4);
  _Float16* a_f16 = (_Float16*)alloc((size_t)MTOK * DIM * 2);
  float*    tmp   = (float*)alloc((size_t)MTOK * DIM * 4);
  _Float16* q_f16 = (_Float16*)alloc((size_t)MTOK * DIM * 2);
  _Float16* k_f16 = (_Float16*)alloc((size_t)MTOK * DIM * 2);
  _Float16* v_f16 = (_Float16*)alloc((size_t)MTOK * DIM * 2);
  _Float16* c_f16 = (_Float16*)alloc((size_t)MTOK * DIM * 2);
  _Float16* ff_f16 = (_Float16*)alloc((size_t)MTOK * FFD * 2);
  float*    ps_all = (float*)alloc((size_t)NL * NB * SEQ * 4);

  // weight transpose/convert (f32 [K][N] -> f16 [N][K])
  transpose_k<<<dim3(24, 24, NL), 256, 0, stream>>>(Wq,  wqT,  DIM, DIM);
  transpose_k<<<dim3(24, 24, NL), 256, 0, stream>>>(Wk,  wkT,  DIM, DIM);
  transpose_k<<<dim3(24, 24, NL), 256, 0, stream>>>(Wv,  wvT,  DIM, DIM);
  transpose_k<<<dim3(24, 24, NL), 256, 0, stream>>>(Wo,  woT,  DIM, DIM);
  transpose_k<<<dim3(96, 24, NL), 256, 0, stream>>>(Wi,  wiT,  DIM, FFD);
  transpose_k<<<dim3(24, 96, NL), 256, 0, stream>>>(Wo2, wo2T, FFD, DIM);
  ps_k<<<NB, 512, 0, stream>>>(epid, coef, ps_all);
  embed_ln_k<<<MTOK, 256, 0, stream>>>(ids, we, pe, elng, elnb, h_f32, h_f16);

  for (int l = 0; l < NL; ++l) {
    gemm_f16<false, false, false, true><<<dim3(6, 64), 256, 0, stream>>>(
        h_f16, wqT + (size_t)l * WSM, bq + l * DIM, nullptr, nullptr, q_f16, MTOK, DIM, DIM);
    gemm_f16<false, false, false, true><<<dim3(6, 64), 256, 0, stream>>>(
        h_f16, wkT + (size_t)l * WSM, bk + l * DIM, nullptr, nullptr, k_f16, MTOK, DIM, DIM);
    gemm_f16<false, false, false, true><<<dim3(6, 64), 256, 0, stream>>>(
        h_f16, wvT + (size_t)l * WSM, bv + l * DIM, nullptr, nullptr, v_f16, MTOK, DIM, DIM);
    attn_k<<<dim3(4, NH, NB), 256, 0, stream>>>(
        q_f16, k_f16, v_f16, ps_all + (size_t)l * NB * SEQ, mask, c_f16);
    gemm_f16<true, false, true, false><<<dim3(6, 64), 256, 0, stream>>>(
        c_f16, woT + (size_t)l * WSM, bo + l * DIM, h_f32, tmp, nullptr, MTOK, DIM, DIM);
    ln_k<<<MTOK, 256, 0, stream>>>(tmp, ln1g + l * DIM, ln1b + l * DIM, a_f32, a_f16);
    gemm_f16<false, true, false, true><<<dim3(24, 64), 256, 0, stream>>>(
        a_f16, wiT + (size_t)l * WLG, bi + l * FFD, nullptr, nullptr, ff_f16, MTOK, FFD, DIM);
    gemm_f16<true, false, true, false><<<dim3(6, 64), 256, 0, stream>>>(
        ff_f16, wo2T + (size_t)l * WLG, bo2 + l * DIM, a_f32, tmp, nullptr, MTOK, DIM, FFD);
    ln_k<<<MTOK, 256, 0, stream>>>(tmp, ln2g + l * DIM, ln2b + l * DIM,
                                   (l == NL - 1) ? out : h_f32, h_f16);
  }
}

// Round 5
// 4658.460 us; speedup vs baseline: 1.0895x; 1.0895x over previous
//
#include <hip/hip_runtime.h>

#define SEQ 512
#define NB  16
#define DIM 768
#define NH  12
#define HDIM 64
#define NL  12
#define FFD 3072
#define MTOK 8192   // NB*SEQ
#define QKVD 2304   // fused QKV row stride

typedef _Float16 half8 __attribute__((ext_vector_type(8)));
typedef float    floatx4 __attribute__((ext_vector_type(4)));

__device__ __forceinline__ void load_lds16(const void* g, void* l) {
  __builtin_amdgcn_global_load_lds((__attribute__((address_space(1))) void*)g,
                                   (__attribute__((address_space(3))) void*)l, 16, 0, 0);
}

// ---------------------------------------------------------------- block LN
__device__ __forceinline__ float blockSum768(float v) {
  __shared__ float red[4];
  #pragma unroll
  for (int d = 32; d; d >>= 1) v += __shfl_xor(v, d);
  const int wv = threadIdx.x >> 6;
  __syncthreads();                 // protect red from previous use
  if ((threadIdx.x & 63) == 0) red[wv] = v;
  __syncthreads();
  return red[0] + red[1] + red[2] + red[3];
}

__device__ __forceinline__ void ln_store(float x0, float x1, float x2,
                                         const float* __restrict__ g,
                                         const float* __restrict__ bb,
                                         float* __restrict__ yf,
                                         _Float16* __restrict__ yh, int row) {
  const int tid = threadIdx.x;
  const float mu = blockSum768(x0 + x1 + x2) * (1.0f / 768.0f);
  const float d0 = x0 - mu, d1 = x1 - mu, d2 = x2 - mu;
  const float var = blockSum768(d0 * d0 + d1 * d1 + d2 * d2) * (1.0f / 768.0f);
  const float inv = rsqrtf(var + 1e-12f);
  const size_t base = (size_t)row * DIM;
  const float y0 = d0 * inv * g[tid]       + bb[tid];
  const float y1 = d1 * inv * g[tid + 256] + bb[tid + 256];
  const float y2 = d2 * inv * g[tid + 512] + bb[tid + 512];
  if (yf) { yf[base + tid] = y0; yf[base + tid + 256] = y1; yf[base + tid + 512] = y2; }
  yh[base + tid] = (_Float16)y0; yh[base + tid + 256] = (_Float16)y1; yh[base + tid + 512] = (_Float16)y2;
}

// ---------------------------------------------------------------- kernels
__global__ __launch_bounds__(256) void embed_ln_k(const int* __restrict__ ids,
                                                  const float* __restrict__ we,
                                                  const float* __restrict__ pe,
                                                  const float* __restrict__ g,
                                                  const float* __restrict__ bb,
                                                  float* __restrict__ hf,
                                                  _Float16* __restrict__ hh) {
  const int tok = blockIdx.x;
  const int s = tok & (SEQ - 1);
  const int id = ids[tok];
  const int tid = threadIdx.x;
  float x[3];
  #pragma unroll
  for (int j = 0; j < 3; ++j) {
    const int d = tid + j * 256;
    x[j] = we[(size_t)id * DIM + d] + pe[(size_t)s * DIM + d];
  }
  ln_store(x[0], x[1], x[2], g, bb, hf, hh, tok);
}

__global__ __launch_bounds__(256) void ln_k(const float* __restrict__ xin,
                                            const float* __restrict__ g,
                                            const float* __restrict__ bb,
                                            float* __restrict__ yf,
                                            _Float16* __restrict__ yh) {
  const int row = blockIdx.x;
  const int tid = threadIdx.x;
  float x[3];
  #pragma unroll
  for (int j = 0; j < 3; ++j) x[j] = xin[(size_t)row * DIM + tid + j * 256];
  ln_store(x[0], x[1], x[2], g, bb, yf, yh, row);
}

// transpose+convert: in f32 [z][K][N] -> out f16 [z-stride ozs][N][K]
__global__ __launch_bounds__(256) void transpose_k(const float* __restrict__ in,
                                                   _Float16* __restrict__ out,
                                                   int K, int N, size_t ozs) {
  __shared__ float tile[32][33];
  const int z = blockIdx.z;
  in  += (size_t)z * K * N;
  out += (size_t)z * ozs;
  const int n0 = blockIdx.x * 32, k0 = blockIdx.y * 32;
  const int tx = threadIdx.x & 31, ty = threadIdx.x >> 5;   // ty 0..7
  #pragma unroll
  for (int i = 0; i < 32; i += 8) tile[ty + i][tx] = in[(size_t)(k0 + ty + i) * N + n0 + tx];
  __syncthreads();
  #pragma unroll
  for (int i = 0; i < 32; i += 8) out[(size_t)(n0 + ty + i) * K + k0 + tx] = (_Float16)tile[tx][ty + i];
}

// concat bq|bk|bv -> biasqkv[l][2304]
__global__ __launch_bounds__(256) void concat_bias_k(const float* __restrict__ bq,
                                                     const float* __restrict__ bk,
                                                     const float* __restrict__ bv,
                                                     float* __restrict__ dst) {
  const int l = blockIdx.x;
  for (int j = threadIdx.x; j < DIM; j += 256) {
    dst[(size_t)l * QKVD + j]           = bq[l * DIM + j];
    dst[(size_t)l * QKVD + DIM + j]     = bk[l * DIM + j];
    dst[(size_t)l * QKVD + 2 * DIM + j] = bv[l * DIM + j];
  }
}

// position-coefficient modulation ps[l][b][s]
__global__ __launch_bounds__(512) void ps_k(const int* __restrict__ epid,
                                            const float* __restrict__ coef,
                                            float* __restrict__ ps_all) {
  __shared__ int red[8];
  const int b = blockIdx.x, tid = threadIdx.x;
  int e = (tid < 256) ? epid[b * 256 + tid] : 0;
  #pragma unroll
  for (int d = 32; d; d >>= 1) e = max(e, __shfl_xor(e, d));
  if ((tid & 63) == 0) red[tid >> 6] = e;
  __syncthreads();
  int turn = red[0];
  #pragma unroll
  for (int i = 1; i < 8; ++i) turn = max(turn, red[i]);
  int row = (turn - 1) >> 1;
  row = max(0, min(4, row));
  const int pe = (tid < 256) ? epid[b * 256 + tid] : 11;
  #pragma unroll
  for (int l = 0; l < NL; ++l)
    ps_all[((size_t)l * NB + b) * SEQ + tid] = coef[(l * 5 + row) * 12 + pe];
}

// ------------------------------------------------------- generic f16 GEMM
// C[M,N] = A[M,K] @ Bt[N,K]^T (+bias, +resid, gelu) ; 128x128 tile, 4 waves
template <bool RES, bool GELU, bool WF, bool WH>
__global__ __launch_bounds__(256) void gemm_f16(const _Float16* __restrict__ A,
                                                const _Float16* __restrict__ Bt,
                                                const float* __restrict__ bias,
                                                const float* __restrict__ resid,
                                                float* __restrict__ outF,
                                                _Float16* __restrict__ outH,
                                                int M, int N, int K) {
  __shared__ __align__(16) _Float16 Als[128 * 32];
  __shared__ __align__(16) _Float16 Bls[128 * 32];
  const int tid = threadIdx.x, lane = tid & 63, wave = tid >> 6;
  const int bm0 = blockIdx.y * 128, bn0 = blockIdx.x * 128;
  const int lr = lane & 15, lk = lane >> 4;
  const int wm = (wave >> 1) * 64, wn = (wave & 1) * 64;
  floatx4 acc[4][4] = {};

  const int srow = lane >> 2;            // 0..15
  const int scol = (lane & 3) * 8;       // 0/8/16/24
  const _Float16* Ag = A  + (size_t)(bm0 + wave * 16 + srow) * K + scol;
  const _Float16* Bg = Bt + (size_t)(bn0 + wave * 16 + srow) * K + scol;
  _Float16* Al = &Als[wave * 16 * 32];
  _Float16* Bl = &Bls[wave * 16 * 32];
  const size_t rs64 = (size_t)64 * K;

  for (int kt = 0; kt < K; kt += 32) {
    load_lds16(Ag + kt,        Al);
    load_lds16(Ag + rs64 + kt, Al + 64 * 32);
    load_lds16(Bg + kt,        Bl);
    load_lds16(Bg + rs64 + kt, Bl + 64 * 32);
    __syncthreads();
    half8 af[4], bf[4];
    #pragma unroll
    for (int i = 0; i < 4; ++i) {
      af[i] = *(const half8*)&Als[(wm + i * 16 + lr) * 32 + lk * 8];
      bf[i] = *(const half8*)&Bls[(wn + i * 16 + lr) * 32 + lk * 8];
    }
    #pragma unroll
    for (int mi = 0; mi < 4; ++mi)
      #pragma unroll
      for (int ni = 0; ni < 4; ++ni)
        acc[mi][ni] = __builtin_amdgcn_mfma_f32_16x16x32_f16(af[mi], bf[ni], acc[mi][ni], 0, 0, 0);
    __syncthreads();
  }

  #pragma unroll
  for (int mi = 0; mi < 4; ++mi) {
    #pragma unroll
    for (int r = 0; r < 4; ++r) {
      const int row = bm0 + wm + mi * 16 + lk * 4 + r;
      const size_t ro = (size_t)row * N;
      #pragma unroll
      for (int ni = 0; ni < 4; ++ni) {
        const int col = bn0 + wn + ni * 16 + lr;
        float x = acc[mi][ni][r] + bias[col];
        if (RES)  x += resid[ro + col];
        if (GELU) x = 0.5f * x * (1.0f + erff(x * 0.70710678118654752f));
        if (WF) outF[ro + col] = x;
        if (WH) outH[ro + col] = (_Float16)x;
      }
    }
  }
}

// ------------------------------------------------------- flash attention
// grid (qt=4, h=12, b=16), 256 threads; wave w owns q-rows qt*128+w*32..+32
// qkv layout: [tok][2304] with q at +0, k at +768, v at +1536
// LDS XOR swizzle: col' = col ^ ((row&7)*8) on kls/vtls/pls (128B rows)
__global__ __launch_bounds__(256) void attn_k(const _Float16* __restrict__ qkv,
                                              const float* __restrict__ ps,
                                              const float* __restrict__ mask,
                                              _Float16* __restrict__ ctx) {
  __shared__ __align__(16) _Float16 kls[64 * 64];
  __shared__ __align__(16) _Float16 vtls[64 * 64];
  __shared__ __align__(16) _Float16 pls[4][32 * 64];
  const int tid = threadIdx.x, lane = tid & 63, wave = tid >> 6;
  const int qt = 3 - blockIdx.x;           // heavy blocks first
  const int h = blockIdx.y, b = blockIdx.z;
  const int lr = lane & 15, lk = lane >> 4;
  const int q0 = qt * 128 + wave * 32;

  half8 qf[2][2];
  #pragma unroll
  for (int mi = 0; mi < 2; ++mi)
    #pragma unroll
    for (int ks = 0; ks < 2; ++ks)
      qf[mi][ks] = *(const half8*)&qkv[(size_t)(b * SEQ + q0 + mi * 16 + lr) * QKVD + h * HDIM + ks * 32 + lk * 8];

  floatx4 o[2][4] = {};
  float m_run[2][4], l_run[2][4], mq[2][4];
  #pragma unroll
  for (int mi = 0; mi < 2; ++mi)
    #pragma unroll
    for (int r = 0; r < 4; ++r) {
      m_run[mi][r] = -3e38f; l_run[mi][r] = 0.f;
      mq[mi][r] = mask[b * SEQ + q0 + mi * 16 + lk * 4 + r];
    }

  const int swzA = (lr & 7) * 8;           // read-side XOR (row&7 == lr&7)
  const int nt = 2 * (qt + 1);
  for (int t = 0; t < nt; ++t) {
    const int kb = t * 64;
    #pragma unroll
    for (int i = 0; i < 2; ++i) {
      const int idx = tid + i * 256;
      // K: coalesced rows, swizzled half8 store
      const int key = idx >> 3, c8 = (idx & 7) * 8;
      *(half8*)&kls[key * 64 + (c8 ^ ((key & 7) * 8))] =
          *(const half8*)&qkv[(size_t)(b * SEQ + kb + key) * QKVD + DIM + h * HDIM + c8];
      // V: key-per-lane mapping -> transpose scatter spreads all 32 banks
      const int keyv = idx & 63, c8v = (idx >> 6) * 8;
      half8 vv = *(const half8*)&qkv[(size_t)(b * SEQ + kb + keyv) * QKVD + 2 * DIM + h * HDIM + c8v];
      #pragma unroll
      for (int j = 0; j < 8; ++j) {
        const int d = c8v + j;
        vtls[d * 64 + (keyv ^ ((d & 7) * 8))] = vv[j];
      }
    }
    __syncthreads();

    // S = Q K^T
    floatx4 s[2][4] = {};
    #pragma unroll
    for (int ks = 0; ks < 2; ++ks)
      #pragma unroll
      for (int ni = 0; ni < 4; ++ni) {
        half8 kf = *(const half8*)&kls[(ni * 16 + lr) * 64 + ((ks * 32 + lk * 8) ^ swzA)];
        #pragma unroll
        for (int mi = 0; mi < 2; ++mi)
          s[mi][ni] = __builtin_amdgcn_mfma_f32_16x16x32_f16(qf[mi][ks], kf, s[mi][ni], 0, 0, 0);
      }

    float pk[4], km[4]; int kidx[4];
    #pragma unroll
    for (int ni = 0; ni < 4; ++ni) {
      kidx[ni] = kb + ni * 16 + lr;
      pk[ni] = ps[b * SEQ + kidx[ni]] * 0.125f;
      km[ni] = mask[b * SEQ + kidx[ni]];
    }

    #pragma unroll
    for (int mi = 0; mi < 2; ++mi) {
      #pragma unroll
      for (int r = 0; r < 4; ++r) {
        const int rq = q0 + mi * 16 + lk * 4 + r;
        const int prow = mi * 16 + lk * 4 + r;
        const int pswz = (prow & 7) * 8;
        float sc[4]; float mt = -3e38f;
        #pragma unroll
        for (int ni = 0; ni < 4; ++ni) {
          const float am = (kidx[ni] <= rq) ? km[ni] * mq[mi][r] : 0.f;
          const float x = s[mi][ni][r] * pk[ni] * am - 1e10f * (1.f - am);
          sc[ni] = x; mt = fmaxf(mt, x);
        }
        #pragma unroll
        for (int d = 1; d < 16; d <<= 1) mt = fmaxf(mt, __shfl_xor(mt, d));
        const float mnew = fmaxf(m_run[mi][r], mt);
        const float corr = __expf(m_run[mi][r] - mnew);
        float rsum = 0.f;
        #pragma unroll
        for (int ni = 0; ni < 4; ++ni) {
          const float p = __expf(sc[ni] - mnew);
          rsum += p;
          pls[wave][prow * 64 + ((ni * 16 + lr) ^ pswz)] = (_Float16)p;
        }
        #pragma unroll
        for (int d = 1; d < 16; d <<= 1) rsum += __shfl_xor(rsum, d);
        l_run[mi][r] = l_run[mi][r] * corr + rsum;
        m_run[mi][r] = mnew;
        #pragma unroll
        for (int ni = 0; ni < 4; ++ni) o[mi][ni][r] *= corr;
      }
    }

    // O += P V
    #pragma unroll
    for (int mi = 0; mi < 2; ++mi) {
      half8 pf[2];
      #pragma unroll
      for (int ks = 0; ks < 2; ++ks)
        pf[ks] = *(const half8*)&pls[wave][(mi * 16 + lr) * 64 + ((ks * 32 + lk * 8) ^ swzA)];
      #pragma unroll
      for (int ni = 0; ni < 4; ++ni)
        #pragma unroll
        for (int ks = 0; ks < 2; ++ks)
          o[mi][ni] = __builtin_amdgcn_mfma_f32_16x16x32_f16(
              pf[ks], *(const half8*)&vtls[(ni * 16 + lr) * 64 + ((ks * 32 + lk * 8) ^ swzA)], o[mi][ni], 0, 0, 0);
    }
    __syncthreads();
  }

  #pragma unroll
  for (int mi = 0; mi < 2; ++mi)
    #pragma unroll
    for (int r = 0; r < 4; ++r) {
      const float inv = 1.f / l_run[mi][r];
      const int rq = q0 + mi * 16 + lk * 4 + r;
      #pragma unroll
      for (int ni = 0; ni < 4; ++ni)
        ctx[(size_t)(b * SEQ + rq) * DIM + h * HDIM + ni * 16 + lr] = (_Float16)(o[mi][ni][r] * inv);
    }
}

// ---------------------------------------------------------------- launch
extern "C" void kernel_launch(void* const* d_in, const int* in_sizes, int n_in,
                              void* d_out, int out_size, void* d_ws, size_t ws_size,
                              hipStream_t stream) {
  const int*   ids  = (const int*)d_in[0];
  const float* mask = (const float*)d_in[1];
  const int*   epid = (const int*)d_in[2];
  const float* we   = (const float*)d_in[3];
  const float* pe   = (const float*)d_in[4];
  const float* elng = (const float*)d_in[5];
  const float* elnb = (const float*)d_in[6];
  const float* Wq   = (const float*)d_in[7];  const float* bq  = (const float*)d_in[8];
  const float* Wk   = (const float*)d_in[9];  const float* bk  = (const float*)d_in[10];
  const float* Wv   = (const float*)d_in[11]; const float* bv  = (const float*)d_in[12];
  const float* Wo   = (const float*)d_in[13]; const float* bo  = (const float*)d_in[14];
  const float* ln1g = (const float*)d_in[15]; const float* ln1b = (const float*)d_in[16];
  const float* Wi   = (const float*)d_in[17]; const float* bi  = (const float*)d_in[18];
  const float* Wo2  = (const float*)d_in[19]; const float* bo2 = (const float*)d_in[20];
  const float* ln2g = (const float*)d_in[21]; const float* ln2b = (const float*)d_in[22];
  const float* coef = (const float*)d_in[23];
  float* out = (float*)d_out;

  char* w = (char*)d_ws;
  auto alloc = [&](size_t bytes) { char* p = w; w += (bytes + 255) & ~(size_t)255; return p; };
  const size_t WSM = (size_t)DIM * DIM;     // 589824
  const size_t WLG = (size_t)DIM * FFD;     // 2359296
  _Float16* wqkvT = (_Float16*)alloc(NL * 3 * WSM * 2);
  _Float16* woT   = (_Float16*)alloc(NL * WSM * 2);
  _Float16* wiT   = (_Float16*)alloc(NL * WLG * 2);
  _Float16* wo2T  = (_Float16*)alloc(NL * WLG * 2);
  float*    bqkv  = (float*)alloc((size_t)NL * QKVD * 4);
  float*    h_f32 = (float*)alloc((size_t)MTOK * DIM * 4);
  _Float16* h_f16 = (_Float16*)alloc((size_t)MTOK * DIM * 2);
  float*    a_f32 = (float*)alloc((size_t)MTOK * DIM * 4);
  _Float16* a_f16 = (_Float16*)alloc((size_t)MTOK * DIM * 2);
  float*    tmp   = (float*)alloc((size_t)MTOK * DIM * 4);
  _Float16* qkv_f16 = (_Float16*)alloc((size_t)MTOK * QKVD * 2);
  _Float16* c_f16 = (_Float16*)alloc((size_t)MTOK * DIM * 2);
  _Float16* ff_f16 = (_Float16*)alloc((size_t)MTOK * FFD * 2);
  float*    ps_all = (float*)alloc((size_t)NL * NB * SEQ * 4);

  // weight transpose/convert (f32 [K][N] -> f16 [N][K]); QKV rows fused
  transpose_k<<<dim3(24, 24, NL), 256, 0, stream>>>(Wq, wqkvT,           DIM, DIM, 3 * WSM);
  transpose_k<<<dim3(24, 24, NL), 256, 0, stream>>>(Wk, wqkvT + WSM,     DIM, DIM, 3 * WSM);
  transpose_k<<<dim3(24, 24, NL), 256, 0, stream>>>(Wv, wqkvT + 2 * WSM, DIM, DIM, 3 * WSM);
  transpose_k<<<dim3(24, 24, NL), 256, 0, stream>>>(Wo,  woT,  DIM, DIM, WSM);
  transpose_k<<<dim3(96, 24, NL), 256, 0, stream>>>(Wi,  wiT,  DIM, FFD, WLG);
  transpose_k<<<dim3(24, 96, NL), 256, 0, stream>>>(Wo2, wo2T, FFD, DIM, WLG);
  concat_bias_k<<<NL, 256, 0, stream>>>(bq, bk, bv, bqkv);
  ps_k<<<NB, 512, 0, stream>>>(epid, coef, ps_all);
  embed_ln_k<<<MTOK, 256, 0, stream>>>(ids, we, pe, elng, elnb, h_f32, h_f16);

  for (int l = 0; l < NL; ++l) {
    gemm_f16<false, false, false, true><<<dim3(18, 64), 256, 0, stream>>>(
        h_f16, wqkvT + (size_t)l * 3 * WSM, bqkv + (size_t)l * QKVD, nullptr,
        nullptr, qkv_f16, MTOK, QKVD, DIM);
    attn_k<<<dim3(4, NH, NB), 256, 0, stream>>>(
        qkv_f16, ps_all + (size_t)l * NB * SEQ, mask, c_f16);
    gemm_f16<true, false, true, false><<<dim3(6, 64), 256, 0, stream>>>(
        c_f16, woT + (size_t)l * WSM, bo + l * DIM, h_f32, tmp, nullptr, MTOK, DIM, DIM);
    ln_k<<<MTOK, 256, 0, stream>>>(tmp, ln1g + l * DIM, ln1b + l * DIM, a_f32, a_f16);
    gemm_f16<false, true, false, true><<<dim3(24, 64), 256, 0, stream>>>(
        a_f16, wiT + (size_t)l * WLG, bi + l * FFD, nullptr, nullptr, ff_f16, MTOK, FFD, DIM);
    gemm_f16<true, false, true, false><<<dim3(6, 64), 256, 0, stream>>>(
        ff_f16, wo2T + (size_t)l * WLG, bo2 + l * DIM, a_f32, tmp, nullptr, MTOK, DIM, FFD);
    ln_k<<<MTOK, 256, 0, stream>>>(tmp, ln2g + l * DIM, ln2b + l * DIM,
                                   (l == NL - 1) ? out : h_f32, h_f16);
  }
}